// Round 9
// baseline (68.810 us; speedup 1.0000x reference)
//
#include <hip/hip_runtime.h>
#include <hip/hip_bf16.h>

// Grouped linear: concat(x0..x3) rows [M=294912, K=128] @ W^T[128,128] + bias -> fp32 out.
// R9: R3 structure at 20 waves/CU. LDS = W only (exactly 32768 B -> 5 blocks/CU);
// bias via per-lane f4 chunk + __shfl broadcast (anti-CSE'd); VGPR capped 102 via
// __launch_bounds__(256,5); 1-deep pipeline (occupancy replaces pipelining);
// regular f32x4 stores (nt amplified writes: 165-199 vs 147 MB). 1152 blocks all co-resident.

typedef __attribute__((ext_vector_type(8))) short bf8_t;   // 8 x bf16 (4 VGPRs)
typedef __attribute__((ext_vector_type(4))) float f4_t;

__device__ __forceinline__ short bfc(float f) {
    // compiler pairs these into v_cvt_pk_bf16_f32 (RNE)
    return __builtin_bit_cast(short, __float2bfloat16(f));
}

__device__ __forceinline__ unsigned short f2bf_rne(float f) {
    unsigned u = __builtin_bit_cast(unsigned, f);
    u += 0x7fffu + ((u >> 16) & 1u);
    return (unsigned short)(u >> 16);
}

#define SEG0 131072L   // rows in x0 (32*64*64)
#define SEG1 196608L   // + x1 (32*32*64)
#define SEG2 262144L   // + x2 (32*64*32)
// all boundaries are multiples of 256 -> per-lane resolve within a 256-row block is exact.

__global__ __launch_bounds__(256, 5)
void lin_kernel(const float* __restrict__ x0, const float* __restrict__ x1,
                const float* __restrict__ x2, const float* __restrict__ x3,
                const float* __restrict__ W, const float* __restrict__ bias,
                float* __restrict__ out)
{
    __shared__ unsigned short Wl[128 * 128]; // bf16 W, exactly 32768 B (5 blocks/CU)

    const int tid = threadIdx.x;

    // ---- stage W: fp32 -> bf16, swizzled (chunk ^= row&7 breaks the 16-way bank conflict) ----
#pragma unroll
    for (int i = 0; i < 16; ++i) {
        int f  = i * 256 + tid;       // float4 index in W, 0..4095
        int n  = f >> 5;              // W row (output feature)
        int k4 = f & 31;              // float4 index within row
        f4_t v = reinterpret_cast<const f4_t*>(W)[f];
        unsigned long long p =
              (unsigned long long)f2bf_rne(v.x)
            | ((unsigned long long)f2bf_rne(v.y) << 16)
            | ((unsigned long long)f2bf_rne(v.z) << 32)
            | ((unsigned long long)f2bf_rne(v.w) << 48);
        int sc = (k4 >> 1) ^ (n & 7); // swizzled 16B-chunk index
        *reinterpret_cast<unsigned long long*>(&Wl[n * 128 + sc * 8 + (k4 & 1) * 4]) = p;
    }
    __syncthreads();

    const int wave = tid >> 6;
    const int lane = tid & 63;
    const int lm   = lane & 15;   // x-row-within-tile
    const int lk   = lane >> 4;   // 0..3 (k-group)
    const int nsw  = lm & 7;      // swizzle key for W reads

    // per-lane bias chunk: lane holds bias[4*(lane&31) .. +3]; broadcast via shfl per tile
    const f4_t bb = *reinterpret_cast<const f4_t*>(bias + ((lane & 31) << 2));

    // block owns 256 rows; wave-tile = 16 rows; tile t rows = t*64 + wave*16 + lm
    const long r0 = (long)blockIdx.x * 256 + wave * 16 + lm;

#pragma unroll
    for (int t = 0; t < 4; ++t) {
        const long gr = r0 + t * 64;

        // resolve segment (per-lane; boundaries all multiples of 64)
        const float* xp; long loc;
        if      (gr < SEG0) { xp = x0; loc = gr; }
        else if (gr < SEG1) { xp = x1; loc = gr - SEG0; }
        else if (gr < SEG2) { xp = x2; loc = gr - SEG1; }
        else                { xp = x3; loc = gr - SEG2; }
        const float* xr   = xp + loc * 128;
        float*       orow = out + gr * 128;

        // ---- load this lane's 32 floats of row gr (8x dwordx4) ----
        f4_t raw[8];
#pragma unroll
        for (int ks = 0; ks < 4; ++ks) {
            const float* p = xr + ks * 32 + lk * 8;
            raw[2 * ks]     = *reinterpret_cast<const f4_t*>(p);
            raw[2 * ks + 1] = *reinterpret_cast<const f4_t*>(p + 4);
        }

        // ---- convert to bf16 B-fragments: lane holds B[k=lk*8+j][n=lm] ----
        bf8_t xf[4];
#pragma unroll
        for (int ks = 0; ks < 4; ++ks) {
            f4_t a = raw[2 * ks], b = raw[2 * ks + 1];
            bf8_t w;
            w[0]=bfc(a.x); w[1]=bfc(a.y); w[2]=bfc(a.z); w[3]=bfc(a.w);
            w[4]=bfc(b.x); w[5]=bfc(b.y); w[6]=bfc(b.z); w[7]=bfc(b.w);
            xf[ks] = w;
        }

        // ---- acc init = bias via wave broadcast (anti-CSE: blackboxed zero offset) ----
        int z = 0;
        asm volatile("" : "+v"(z));          // opaque 0: keeps per-tile shfls from CSE/hoist
        const int lkz = lk + z;
        f4_t acc[8];
#pragma unroll
        for (int nt = 0; nt < 8; ++nt) {
#pragma unroll
            for (int e = 0; e < 4; ++e)
                acc[nt][e] = __shfl(bb[e], nt * 4 + lkz);   // = bias[nt*16+lk*4+e]
        }

        // ---- swapped-operand MFMA: A = W tile (16 out-cols x 32 k), B = x^T ----
#pragma unroll
        for (int nt = 0; nt < 8; ++nt) {
            const int nrow = nt * 16 + lm;
#pragma unroll
            for (int ks = 0; ks < 4; ++ks) {
                const int c = (ks * 4 + lk) ^ nsw;  // swizzled 16B chunk
                bf8_t wf = *reinterpret_cast<const bf8_t*>(&Wl[nrow * 128 + c * 8]);
                acc[nt] = __builtin_amdgcn_mfma_f32_16x16x32_bf16(wf, xf[ks], acc[nt], 0, 0, 0);
            }
        }

        // ---- coalesced regular f32x4 stores (lane covers 4 consecutive cols) ----
#pragma unroll
        for (int nt = 0; nt < 8; ++nt)
            *reinterpret_cast<f4_t*>(orow + nt * 16 + lk * 4) = acc[nt];
    }
}

extern "C" void kernel_launch(void* const* d_in, const int* in_sizes, int n_in,
                              void* d_out, int out_size, void* d_ws, size_t ws_size,
                              hipStream_t stream) {
    const float* x0 = (const float*)d_in[0];
    const float* x1 = (const float*)d_in[1];
    const float* x2 = (const float*)d_in[2];
    const float* x3 = (const float*)d_in[3];
    const float* W  = (const float*)d_in[4];
    const float* b  = (const float*)d_in[5];
    float* out = (float*)d_out;

    // 294912 rows / 256 rows per block = 1152 blocks; 5 blocks/CU resident -> all co-resident
    hipLaunchKernelGGL(lin_kernel, dim3(1152), dim3(256), 0, stream,
                       x0, x1, x2, x3, W, b, out);
}

// Round 10
// 63.365 us; speedup vs baseline: 1.0859x; 1.0859x over previous
//
#include <hip/hip_runtime.h>
#include <hip/hip_bf16.h>

// Grouped linear: concat(x0..x3) rows [M=294912, K=128] @ W^T[128,128] + bias -> fp32 out.
// R10: T3/T4 pipeline. x staged global->LDS (global_load_lds w=16, source-side XOR swizzle),
// 3 x 16KB buffers (32-row tiles), 2 tiles prefetch-ahead, COUNTED s_waitcnt vmcnt(8)
// (never drain) + raw s_barrier. W in registers per wave (32-feature strip, loaded once).
// 768 blocks x 256 threads = 3 blocks/CU (48KB LDS), all co-resident, zero tail.

typedef __attribute__((ext_vector_type(8))) short bf8_t;   // 8 x bf16 (4 VGPRs)
typedef __attribute__((ext_vector_type(4))) float f4_t;

typedef const unsigned __attribute__((address_space(1)))* gp_t;
typedef unsigned __attribute__((address_space(3)))* lp_t;

__device__ __forceinline__ short bfc(float f) {
    // compiler pairs these into v_cvt_pk_bf16_f32 (RNE)
    return __builtin_bit_cast(short, __float2bfloat16(f));
}

#define SEG0 131072L   // rows in x0 (32*64*64)
#define SEG1 196608L   // + x1 (32*32*64)
#define SEG2 262144L   // + x2 (32*64*32)
// all boundaries are multiples of 32 -> every 32-row tile is single-segment.

__device__ __forceinline__ const float* tile_src(long gr,
    const float* __restrict__ x0, const float* __restrict__ x1,
    const float* __restrict__ x2, const float* __restrict__ x3)
{
    const float* xp; long loc;
    if      (gr < SEG0) { xp = x0; loc = gr; }
    else if (gr < SEG1) { xp = x1; loc = gr - SEG0; }
    else if (gr < SEG2) { xp = x2; loc = gr - SEG1; }
    else                { xp = x3; loc = gr - SEG2; }
    return xp + loc * 128;
}

// Stage one 32x128 fp32 tile (16 KB) into LDS: 4 global_load_lds(16B) per thread.
// LDS dest linear (wave-uniform base + lane*16 by HW); XOR swizzle applied on the
// GLOBAL SOURCE side (rule #21): LDS chunk (r,kc) holds global chunk (r, kc^(r&7)).
__device__ __forceinline__ void stage_tile(const float* __restrict__ src,
                                           float* __restrict__ buf, int tid)
{
#pragma unroll
    for (int i = 0; i < 4; ++i) {
        const int c  = i * 256 + tid;    // 16B-chunk index 0..1023
        const int r  = c >> 5;           // row 0..31
        const int kc = c & 31;           // chunk within row
        const float* g = src + r * 128 + ((kc ^ (r & 7)) << 2);
        float* l = buf + (c & ~63) * 4;  // wave-uniform base; +lane*16B implicit
        __builtin_amdgcn_global_load_lds((gp_t)g, (lp_t)l, 16, 0, 0);
    }
}

// Compute 32 rows x this wave's 32 features from the staged tile (R8-verified layout).
__device__ __forceinline__ void compute_tile(const float* __restrict__ buf,
    float* __restrict__ obase, const bf8_t (&wf)[2][4],
    f4_t bf0, f4_t bf1, int wave, int lm, int lk)
{
#pragma unroll
    for (int s = 0; s < 2; ++s) {
        const int row = s * 16 + lm;
        const int sw  = row & 7;
        // lane needs x[row][k = ks*32 + lk*8 + (0..7)] = global chunks ks*8+lk*2+{0,1}
        bf8_t xf[4];
#pragma unroll
        for (int ks = 0; ks < 4; ++ks) {
            const int c0 = ks * 8 + lk * 2;
            f4_t a = *reinterpret_cast<const f4_t*>(buf + row * 128 + (((c0    ) ^ sw) << 2));
            f4_t b = *reinterpret_cast<const f4_t*>(buf + row * 128 + (((c0 + 1) ^ sw) << 2));
            bf8_t t;
            t[0]=bfc(a.x); t[1]=bfc(a.y); t[2]=bfc(a.z); t[3]=bfc(a.w);
            t[4]=bfc(b.x); t[5]=bfc(b.y); t[6]=bfc(b.z); t[7]=bfc(b.w);
            xf[ks] = t;
        }
        // D: col = lane&15 = x-row, feature = wave*32 + nt*16 + lk*4 + reg
        f4_t acc0 = bf0, acc1 = bf1;
#pragma unroll
        for (int ks = 0; ks < 4; ++ks) {
            acc0 = __builtin_amdgcn_mfma_f32_16x16x32_bf16(wf[0][ks], xf[ks], acc0, 0, 0, 0);
            acc1 = __builtin_amdgcn_mfma_f32_16x16x32_bf16(wf[1][ks], xf[ks], acc1, 0, 0, 0);
        }
        float* orow = obase + (long)row * 128 + wave * 32 + lk * 4;
        *reinterpret_cast<f4_t*>(orow)      = acc0;
        *reinterpret_cast<f4_t*>(orow + 16) = acc1;
    }
}

__global__ __launch_bounds__(256)
void lin_kernel(const float* __restrict__ x0, const float* __restrict__ x1,
                const float* __restrict__ x2, const float* __restrict__ x3,
                const float* __restrict__ W, const float* __restrict__ bias,
                float* __restrict__ out)
{
    __shared__ float sb0[32 * 128];   // 16 KB each, 48 KB total -> 3 blocks/CU
    __shared__ float sb1[32 * 128];
    __shared__ float sb2[32 * 128];

    const int tid  = threadIdx.x;
    const int wave = tid >> 6;
    const int lane = tid & 63;
    const int lm   = lane & 15;   // x-row within 16 / feature-row within 16
    const int lk   = lane >> 4;   // k-subgroup 0..3

    const long blk0 = (long)blockIdx.x * 384;   // block owns 12 tiles of 32 rows

    // ---- W fragments in registers (once per kernel): wave owns features [wave*32,+32) ----
    bf8_t wf[2][4];
#pragma unroll
    for (int nt = 0; nt < 2; ++nt) {
        const int nW = wave * 32 + nt * 16 + lm;
#pragma unroll
        for (int ks = 0; ks < 4; ++ks) {
            const float* p = W + nW * 128 + ks * 32 + lk * 8;
            f4_t a = *reinterpret_cast<const f4_t*>(p);
            f4_t b = *reinterpret_cast<const f4_t*>(p + 4);
            bf8_t t;
            t[0]=bfc(a.x); t[1]=bfc(a.y); t[2]=bfc(a.z); t[3]=bfc(a.w);
            t[4]=bfc(b.x); t[5]=bfc(b.y); t[6]=bfc(b.z); t[7]=bfc(b.w);
            wf[nt][ks] = t;
        }
    }
    const f4_t bf0 = *reinterpret_cast<const f4_t*>(bias + wave * 32 +      lk * 4);
    const f4_t bf1 = *reinterpret_cast<const f4_t*>(bias + wave * 32 + 16 + lk * 4);

    // ---- prologue: stage tiles 0,1; peel iter 0 ----
    float *pA = sb0, *pB = sb1, *pC = sb2;  // pA: compute-from; pB: t+1 staged; pC: t+2 target
    stage_tile(tile_src(blk0 +  0, x0, x1, x2, x3), pA, tid);
    stage_tile(tile_src(blk0 + 32, x0, x1, x2, x3), pB, tid);

    asm volatile("s_waitcnt vmcnt(4)" ::: "memory");   // tile0's 4 glds retired (in-order)
    __builtin_amdgcn_s_barrier();
    asm volatile("" ::: "memory");
    stage_tile(tile_src(blk0 + 64, x0, x1, x2, x3), pC, tid);
    compute_tile(pA, out + blk0 * 128, wf, bf0, bf1, wave, lm, lk);

    // ---- main loop: counted vmcnt (never drain), 1 barrier per tile ----
#pragma unroll 1
    for (int t = 1; t < 12; ++t) {
        // outstanding (oldest->youngest): stage(t):4, stores(t-2):4, stage(t+1):4, stores(t-1):4.
        // In-order vmcnt retirement: vmcnt(8) forces stage(t) done, leaves the 8 youngest in flight.
        asm volatile("s_waitcnt vmcnt(8)" ::: "memory");
        __builtin_amdgcn_s_barrier();
        asm volatile("" ::: "memory");
        float* tmp = pA; pA = pB; pB = pC; pC = tmp;     // pA = tile t's buffer
        if (t + 2 < 12)
            stage_tile(tile_src(blk0 + (long)(t + 2) * 32, x0, x1, x2, x3), pC, tid);
        compute_tile(pA, out + (blk0 + (long)t * 32) * 128, wf, bf0, bf1, wave, lm, lk);
    }
}

extern "C" void kernel_launch(void* const* d_in, const int* in_sizes, int n_in,
                              void* d_out, int out_size, void* d_ws, size_t ws_size,
                              hipStream_t stream) {
    const float* x0 = (const float*)d_in[0];
    const float* x1 = (const float*)d_in[1];
    const float* x2 = (const float*)d_in[2];
    const float* x3 = (const float*)d_in[3];
    const float* W  = (const float*)d_in[4];
    const float* b  = (const float*)d_in[5];
    float* out = (float*)d_out;

    // 294912 rows / 384 rows per block = 768 blocks = 3 resident per CU, zero tail
    hipLaunchKernelGGL(lin_kernel, dim3(768), dim3(256), 0, stream,
                       x0, x1, x2, x3, W, b, out);
}